// Round 5
// baseline (2226.125 us; speedup 1.0000x reference)
//
#include <hip/hip_runtime.h>
#include <hip/hip_fp16.h>

// BiLSTM-CRF forward, MI355X. Round 5: k_lstm v5 — 1 wave/SIMD, 512-reg budget.
// WG=256 threads (__launch_bounds__(256,1) -> 512 unified regs/wave).
// Lane tid owns the 4 gate cols of h-index tid -> no gate gather, 1 barrier/step.
// Wh: 92 k2-rows in VGPRs (368 regs), 36 rows in LDS (147KB). Rounds 2-4 failed
// because 2 waves/SIMD caps at 256 regs (demand 296) -> spill; this removes the cap.

typedef unsigned int  uint32;
typedef unsigned short ushort16;
typedef __attribute__((ext_vector_type(8))) short  short8;   // 8 bf16 (4 VGPRs) — MFMA A/B frag
typedef __attribute__((ext_vector_type(4))) float  floatx4;  // MFMA C/D frag
typedef __attribute__((ext_vector_type(2))) _Float16 half2t;

#define BB 64
#define TT 512
#define NT (BB*TT)        // 32768 rows
#define G4 1024           // 4*H
#define NL 9
#define KR2 92            // k2 rows VGPR-resident (92*4 = 368 regs)
#define KL2 36            // k2 rows LDS-resident (36*4KB = 147KB)

__device__ inline float bf2f(ushort16 u) {
  return __builtin_bit_cast(float, ((uint32)u) << 16);
}
__device__ inline ushort16 f2bf(float f) {  // RN-even bf16
  uint32 u = __builtin_bit_cast(uint32, f);
  u += 0x7fffu + ((u >> 16) & 1u);
  return (ushort16)(u >> 16);
}
__device__ inline float sigf(float x)  { return 1.0f / (1.0f + __expf(-x)); }
__device__ inline float tanhf_(float x){ return 1.0f - 2.0f / (1.0f + __expf(2.0f * x)); }

__device__ inline float fdot2_(uint32 w, half2t h, float acc) {
  return __builtin_amdgcn_fdot2(__builtin_bit_cast(half2t, w), h, acc, false);
}

// ---------------- K1: seq_len ----------------
__global__ __launch_bounds__(64) void k_seqlen(const int* __restrict__ tokens,
                                               int* __restrict__ slen,
                                               float* __restrict__ out_sl) {
  const int b = blockIdx.x, lane = threadIdx.x;
  int cnt = 0;
  for (int t = lane; t < TT; t += 64) cnt += (tokens[b * TT + t] != 0) ? 1 : 0;
  #pragma unroll
  for (int off = 32; off >= 1; off >>= 1) cnt += __shfl_down(cnt, off, 64);
  if (lane == 0) { slen[b] = cnt; out_sl[b] = (float)cnt; }
}

// ---------------- K2a: embedding gather -> bf16 A matrix [NT][256] ----------------
__global__ __launch_bounds__(256) void k_embed(const int* __restrict__ tokens,
                                               const float* __restrict__ emb,
                                               ushort16* __restrict__ A) {
  const int f = blockIdx.x * 256 + threadIdx.x;  // float4 group, NT*256/4 total
  const int e = f * 4;
  const int row = e >> 8;
  const int col = e & 255;
  const int tok = tokens[row];
  const float4 v = *(const float4*)(emb + (size_t)tok * 256 + col);
  uint32 lo = (uint32)f2bf(v.x) | ((uint32)f2bf(v.y) << 16);
  uint32 hi = (uint32)f2bf(v.z) | ((uint32)f2bf(v.w) << 16);
  *(uint2*)(A + e) = make_uint2(lo, hi);
}

// ---------------- K2b: BT[c][k] = Wx_{f|b}[k][c] bf16, c in [0,2048) ----------------
__global__ __launch_bounds__(256) void k_wxprep(const float* __restrict__ Wxf,
                                                const float* __restrict__ Wxb,
                                                ushort16* __restrict__ BT) {
  const int id = blockIdx.x * 256 + threadIdx.x;   // 2048*256
  const int c = id >> 8, k = id & 255;
  const float v = (c < G4) ? Wxf[k * G4 + c] : Wxb[k * G4 + (c - G4)];
  BT[c * 256 + k] = f2bf(v);
}

// ---------------- K2c: Wh -> half2 pack, layout [k2][1024] ----------------
__global__ __launch_bounds__(256) void k_whprep(const float* __restrict__ Wh,
                                                uint32* __restrict__ W2) {
  const int id = blockIdx.x * 256 + threadIdx.x;   // 128*1024
  const int k2 = id >> 10, c = id & 1023;
  const float w0 = Wh[(2 * k2) * G4 + c];
  const float w1 = Wh[(2 * k2 + 1) * G4 + c];
  const ushort16 b0 = __builtin_bit_cast(ushort16, (_Float16)w0);
  const ushort16 b1 = __builtin_bit_cast(ushort16, (_Float16)w1);
  W2[id] = ((uint32)b1 << 16) | (uint32)b0;
}

// ---------------- K3: xg GEMM  [NT,256] @ [256,2048] -> bf16 xg (gate-quad layout) ----------------
// Output ushort index = row*1024 + (h_idx)*4 + gate, h_idx=c&255, gate=c>>8 (per dir),
// so k_lstm lane tid reads its 4 gate inputs as ONE 8-byte load.
__global__ __launch_bounds__(256) void k_gemm_xg(const ushort16* __restrict__ A,
                                                 const ushort16* __restrict__ BT,
                                                 const float* __restrict__ bias_f,
                                                 const float* __restrict__ bias_b,
                                                 ushort16* __restrict__ xgf,
                                                 ushort16* __restrict__ xgb) {
  __shared__ __align__(16) ushort16 As[64 * 36];
  __shared__ __align__(16) ushort16 Bs[64 * 36];
  const int m0 = blockIdx.x * 64;
  const int n0 = blockIdx.y * 64;
  const int tid = threadIdx.x;
  const int wave = tid >> 6, lane = tid & 63;
  const int lr = tid >> 2;            // staging row 0..63
  const int lc = (tid & 3) * 8;       // staging col {0,8,16,24}
  const int am = lane & 15, aq = lane >> 4;
  floatx4 acc[4];
  #pragma unroll
  for (int j = 0; j < 4; ++j) acc[j] = (floatx4){0.f, 0.f, 0.f, 0.f};

  for (int k0 = 0; k0 < 256; k0 += 32) {
    const uint4 va = *(const uint4*)(A  + ((m0 + lr) * 256 + k0 + lc));
    const uint4 vb = *(const uint4*)(BT + ((n0 + lr) * 256 + k0 + lc));
    *(uint2*)&As[lr * 36 + lc]     = make_uint2(va.x, va.y);
    *(uint2*)&As[lr * 36 + lc + 4] = make_uint2(va.z, va.w);
    *(uint2*)&Bs[lr * 36 + lc]     = make_uint2(vb.x, vb.y);
    *(uint2*)&Bs[lr * 36 + lc + 4] = make_uint2(vb.z, vb.w);
    __syncthreads();
    union { uint2 u[2]; short8 s; } fa, fb;
    fa.u[0] = *(const uint2*)&As[(wave * 16 + am) * 36 + aq * 8];
    fa.u[1] = *(const uint2*)&As[(wave * 16 + am) * 36 + aq * 8 + 4];
    #pragma unroll
    for (int j = 0; j < 4; ++j) {
      fb.u[0] = *(const uint2*)&Bs[(j * 16 + am) * 36 + aq * 8];
      fb.u[1] = *(const uint2*)&Bs[(j * 16 + am) * 36 + aq * 8 + 4];
      acc[j] = __builtin_amdgcn_mfma_f32_16x16x32_bf16(fa.s, fb.s, acc[j], 0, 0, 0);
    }
    __syncthreads();
  }
  // C/D layout (m89/m91-verified): col = lane&15, row = (lane>>4)*4 + reg
  const int orow = m0 + wave * 16 + aq * 4;
  #pragma unroll
  for (int j = 0; j < 4; ++j) {
    const int col = n0 + j * 16 + am;
    const float bv = (col < G4) ? bias_f[col] : bias_b[col - G4];
    const int cc = col & 1023;
    const int poff = ((cc & 255) << 2) + (cc >> 8);   // h_idx*4 + gate
    ushort16* dst = (col < G4) ? xgf : xgb;
    #pragma unroll
    for (int r = 0; r < 4; ++r) {
      const float v = acc[j][r] + bv;
      const int row = orow + r;
      dst[(size_t)row * G4 + poff] = f2bf(v);
    }
  }
}

// ---------------- K4: LSTM recurrence v5 — 512-reg/wave residency ----------------
// 1 WG per (dir,b); 256 threads (4 waves, 1/SIMD -> 512 unified regs).
// Lane tid owns h-index tid: gate cols {tid,256+tid,512+tid,768+tid}.
// wr[k2] uint4 = W2[k2][{tid,256+tid,512+tid,768+tid}] for k2<KR2 (VGPR);
// k2 in [KR2,128) in LDS as per-lane uint4 (ds_read_b128, conflict-free).
// h broadcast: wave-uniform ds_read_b128 of packed-f16 h, double-buffered,
// ONE barrier per step. c/h never leave the lane.
__global__ __launch_bounds__(256, 1) void k_lstm(const uint2* __restrict__ xg4f,
                                                 const uint2* __restrict__ xg4b,
                                                 const uint32* __restrict__ Whf,
                                                 const uint32* __restrict__ Whb,
                                                 float* __restrict__ enc) {
  __shared__ __align__(16) uint4  WLs[KL2 * 256];   // 147456 B
  __shared__ __align__(16) uint32 h2buf[2 * 128];   // 1 KB packed f16 h
  const int bi = blockIdx.x;
  const int dir = bi >> 6, b = bi & 63;
  const int tid = threadIdx.x;
  const uint2* xg = dir ? xg4b : xg4f;   // gate-quad layout: uint2 idx = row*256 + tid
  const uint32* W2 = dir ? Whb : Whf;

  // Stage LDS-resident k2 rows as per-lane uint4.
  for (int k2r = 0; k2r < KL2; ++k2r) {
    const uint32* src = W2 + (KR2 + k2r) * 1024 + tid;
    WLs[k2r * 256 + tid] = make_uint4(src[0], src[256], src[512], src[768]);
  }
  // VGPR-resident rows.
  uint4 wr[KR2];
  #pragma unroll
  for (int i = 0; i < KR2; ++i) {
    const uint32* src = W2 + i * 1024 + tid;
    wr[i] = make_uint4(src[0], src[256], src[512], src[768]);
  }
  #pragma unroll
  for (int i = 0; i < KR2; ++i)
    asm volatile("" : "+v"(wr[i].x), "+v"(wr[i].y), "+v"(wr[i].z), "+v"(wr[i].w));

  if (tid < 128) h2buf[tid] = 0u;
  float c_state = 0.f;
  __syncthreads();

  const int t0 = dir ? (TT - 1) : 0;
  uint2 xp = xg[(size_t)(b * TT + t0) * 256 + tid];

  for (int s = 0; s < TT; ++s) {
    float a0 = bf2f((ushort16)(xp.x & 0xffffu));
    float a1 = bf2f((ushort16)(xp.x >> 16));
    float a2 = bf2f((ushort16)(xp.y & 0xffffu));
    float a3 = bf2f((ushort16)(xp.y >> 16));
    if (s + 1 < TT) {
      const int t1 = dir ? (TT - 2 - s) : (s + 1);
      xp = xg[(size_t)(b * TT + t1) * 256 + tid];
    }
    const uint4* hb = (const uint4*)(h2buf + (s & 1) * 128);
    // VGPR part: k2 = 0..91  (23 uniform h quad-reads)
    #pragma unroll
    for (int blk = 0; blk < 23; ++blk) {
      const uint4 hq = hb[blk];
      #pragma unroll
      for (int j = 0; j < 4; ++j) {
        const int k2 = blk * 4 + j;
        const uint32 hu = (j == 0) ? hq.x : (j == 1) ? hq.y : (j == 2) ? hq.z : hq.w;
        const half2t hh = __builtin_bit_cast(half2t, hu);
        a0 = fdot2_(wr[k2].x, hh, a0);
        a1 = fdot2_(wr[k2].y, hh, a1);
        a2 = fdot2_(wr[k2].z, hh, a2);
        a3 = fdot2_(wr[k2].w, hh, a3);
      }
    }
    // LDS part: k2 = 92..127 (9 uniform h quad-reads, 36 per-lane b128 weight reads)
    #pragma unroll
    for (int blk = 23; blk < 32; ++blk) {
      const uint4 hq = hb[blk];
      #pragma unroll
      for (int j = 0; j < 4; ++j) {
        const int k2 = blk * 4 + j;
        const uint32 hu = (j == 0) ? hq.x : (j == 1) ? hq.y : (j == 2) ? hq.z : hq.w;
        const half2t hh = __builtin_bit_cast(half2t, hu);
        const uint4 wv = WLs[(k2 - KR2) * 256 + tid];
        a0 = fdot2_(wv.x, hh, a0);
        a1 = fdot2_(wv.y, hh, a1);
        a2 = fdot2_(wv.z, hh, a2);
        a3 = fdot2_(wv.w, hh, a3);
      }
    }
    // Nonlinearity + state update, all lane-local.
    c_state = sigf(a1) * c_state + sigf(a0) * tanhf_(a2);
    const float h = sigf(a3) * tanhf_(c_state);
    const int row = b * TT + (dir ? (TT - 1 - s) : s);
    enc[(size_t)row * 512 + dir * 256 + tid] = h;
    // pack h -> f16 pairs; even lanes write one dword (conflict-free)
    const int hv = (int)(uint32)__builtin_bit_cast(ushort16, (_Float16)h);
    const int ho = __shfl_xor(hv, 1, 64);
    if (!(tid & 1))
      h2buf[((s + 1) & 1) * 128 + (tid >> 1)] =
          ((uint32)hv & 0xffffu) | ((uint32)ho << 16);
    __syncthreads();
  }
}

// ---------------- K5: logits = enc @ W_dense + b ----------------
__global__ __launch_bounds__(256) void k_dense(const float* __restrict__ enc,
                                               const float* __restrict__ Wd,
                                               const float* __restrict__ bd,
                                               float* __restrict__ logits) {
  __shared__ float Wl[512 * NL];
  __shared__ float bl[NL];
  const int tid = threadIdx.x;
  for (int i = tid; i < 512 * NL; i += 256) Wl[i] = Wd[i];
  if (tid < NL) bl[tid] = bd[tid];
  __syncthreads();
  const int wave = tid >> 6, lane = tid & 63;
  const int row = blockIdx.x * 4 + wave;
  const float* er = enc + (size_t)row * 512;
  float p[NL];
  #pragma unroll
  for (int c = 0; c < NL; ++c) p[c] = 0.f;
  #pragma unroll
  for (int u = 0; u < 8; ++u) {
    const int k = u * 64 + lane;
    const float v = er[k];
    const float* wr = &Wl[k * NL];
    #pragma unroll
    for (int c = 0; c < NL; ++c) p[c] += v * wr[c];
  }
  #pragma unroll
  for (int c = 0; c < NL; ++c) {
    #pragma unroll
    for (int off = 32; off >= 1; off >>= 1) p[c] += __shfl_down(p[c], off, 64);
  }
  if (lane == 0) {
    float* orow = logits + (size_t)row * NL;
    #pragma unroll
    for (int c = 0; c < NL; ++c) orow[c] = p[c] + bl[c];
  }
}

// ---------------- K6: CRF log-likelihood ----------------
__global__ __launch_bounds__(64) void k_crf(const float* __restrict__ logits,
                                            const int* __restrict__ labels,
                                            const int* __restrict__ slen,
                                            const float* __restrict__ trans,
                                            float* __restrict__ out_ll) {
  __shared__ float tr[NL * NL];
  __shared__ float alpha[NL];
  const int b = blockIdx.x;
  const int lane = threadIdx.x;
  for (int i = lane; i < NL * NL; i += 64) tr[i] = trans[i];
  __syncthreads();
  const int len = slen[b];
  const int* tg = labels + b * TT;
  const float* lg = logits + (size_t)b * TT * NL;
  float s = 0.f;
  for (int t = lane; t < TT; t += 64)
    if (t < len) s += lg[t * NL + tg[t]];
  for (int t = lane; t < TT - 1; t += 64)
    if (t + 1 < len) s += tr[tg[t] * NL + tg[t + 1]];
  #pragma unroll
  for (int off = 32; off >= 1; off >>= 1) s += __shfl_down(s, off, 64);
  if (lane < NL) alpha[lane] = lg[lane];
  __syncthreads();
  if (lane < NL) {
    const int j = lane;
    for (int t = 1; t < TT; ++t) {
      if (t < len) {
        float av[NL];
        float m = -1e30f;
        #pragma unroll
        for (int i = 0; i < NL; ++i) { av[i] = alpha[i] + tr[i * NL + j]; m = fmaxf(m, av[i]); }
        float ss = 0.f;
        #pragma unroll
        for (int i = 0; i < NL; ++i) ss += __expf(av[i] - m);
        const float nj = m + __logf(ss) + lg[t * NL + j];
        alpha[j] = nj;
      }
    }
  }
  __syncthreads();
  if (lane == 0) {
    float m = -1e30f;
    #pragma unroll
    for (int i = 0; i < NL; ++i) m = fmaxf(m, alpha[i]);
    float ss = 0.f;
    #pragma unroll
    for (int i = 0; i < NL; ++i) ss += __expf(alpha[i] - m);
    out_ll[b] = s - (m + __logf(ss));
  }
}

extern "C" void kernel_launch(void* const* d_in, const int* in_sizes, int n_in,
                              void* d_out, int out_size, void* d_ws, size_t ws_size,
                              hipStream_t stream) {
  (void)in_sizes; (void)n_in; (void)out_size; (void)ws_size;
  const int*   tokens = (const int*)d_in[0];
  const int*   labels = (const int*)d_in[1];
  const float* emb    = (const float*)d_in[2];
  const float* Wxf    = (const float*)d_in[3];
  const float* Whf    = (const float*)d_in[4];
  const float* bf_    = (const float*)d_in[5];
  const float* Wxb    = (const float*)d_in[6];
  const float* Whb    = (const float*)d_in[7];
  const float* bb_    = (const float*)d_in[8];
  const float* Wd     = (const float*)d_in[9];
  const float* bd     = (const float*)d_in[10];
  const float* trans  = (const float*)d_in[11];
  float* out = (float*)d_out;   // [logits 294912][seq_len 64][ll 64]

  char* ws = (char*)d_ws;
  ushort16* A    = (ushort16*)(ws + 0);           // 16 MB  bf16 emb rows
  ushort16* BT   = (ushort16*)(ws + 16777216);    //  1 MB  Wx^T bf16 (2048x256)
  uint32*   W2f  = (uint32*)  (ws + 17825792);    // 512 KB Wh_f half2 [128][1024]
  uint32*   W2b  = (uint32*)  (ws + 18350080);    // 512 KB
  ushort16* xgf  = (ushort16*)(ws + 18874368);    // 64 MB  bf16 gate-quad [NT][1024]
  ushort16* xgb  = (ushort16*)(ws + 85983232);    // 64 MB
  float*    enc  = (float*)   (ws + 153092096);   // 64 MB  fp32 [NT][512]
  int*      slen = (int*)     (ws + 220200960);   // 256 B

  k_seqlen<<<BB, 64, 0, stream>>>(tokens, slen, out + NT * NL);
  k_embed <<<NT * 256 / 4 / 256, 256, 0, stream>>>(tokens, emb, A);
  k_wxprep<<<2048 * 256 / 256, 256, 0, stream>>>(Wxf, Wxb, BT);
  k_whprep<<<128 * 1024 / 256, 256, 0, stream>>>(Whf, W2f);
  k_whprep<<<128 * 1024 / 256, 256, 0, stream>>>(Whb, W2b);
  k_gemm_xg<<<dim3(NT / 64, 2048 / 64), 256, 0, stream>>>(A, BT, bf_, bb_, xgf, xgb);
  k_lstm  <<<128, 256, 0, stream>>>((const uint2*)xgf, (const uint2*)xgb, W2f, W2b, enc);
  k_dense <<<NT / 4, 256, 0, stream>>>(enc, Wd, bd, out);
  k_crf   <<<BB, 64, 0, stream>>>(out, labels, slen, trans, out + NT * NL + BB);
}

// Round 6
// 1786.362 us; speedup vs baseline: 1.2462x; 1.2462x over previous
//
#include <hip/hip_runtime.h>
#include <hip/hip_fp16.h>

// BiLSTM-CRF forward, MI355X. Round 6: k_lstm v6 — three-way weight residency.
// Lesson r2-r5: arch VGPRs cap at 256; unified 512 regs/wave (1 wave/SIMD) is
// only reachable as 256 VGPR + 256 AGPR. Split per-lane weight set (512 dwords):
//   KA=60 k2-rows in AGPRs (240 a-regs, explicit v_accvgpr_write/read — r4-proven),
//   KV=43 rows in VGPRs (172 regs, asm-pinned),
//   KL=25 rows in LDS (100 KB, per-lane ds_read_b128).
// 256 threads/WG, lane owns h-index (4 gate cols), 1 barrier/step.

typedef unsigned int  uint32;
typedef unsigned short ushort16;
typedef __attribute__((ext_vector_type(8))) short  short8;   // 8 bf16 (4 VGPRs) — MFMA A/B frag
typedef __attribute__((ext_vector_type(4))) float  floatx4;  // MFMA C/D frag
typedef __attribute__((ext_vector_type(2))) _Float16 half2t;

#define BB 64
#define TT 512
#define NT (BB*TT)        // 32768 rows
#define G4 1024           // 4*H
#define NL 9
#define KA 60             // k2 rows AGPR-resident (60*4 = 240 a-regs)
#define KV 43             // k2 rows VGPR-resident (43*4 = 172 v-regs)
#define KL 25             // k2 rows LDS-resident  (25*4KB = 100 KB)

__device__ inline float bf2f(ushort16 u) {
  return __builtin_bit_cast(float, ((uint32)u) << 16);
}
__device__ inline ushort16 f2bf(float f) {  // RN-even bf16
  uint32 u = __builtin_bit_cast(uint32, f);
  u += 0x7fffu + ((u >> 16) & 1u);
  return (ushort16)(u >> 16);
}
__device__ inline float sigf(float x)  { return 1.0f / (1.0f + __expf(-x)); }
__device__ inline float tanhf_(float x){ return 1.0f - 2.0f / (1.0f + __expf(2.0f * x)); }

__device__ inline float fdot2_(uint32 w, half2t h, float acc) {
  return __builtin_amdgcn_fdot2(__builtin_bit_cast(half2t, w), h, acc, false);
}

// ---------------- K1: seq_len ----------------
__global__ __launch_bounds__(64) void k_seqlen(const int* __restrict__ tokens,
                                               int* __restrict__ slen,
                                               float* __restrict__ out_sl) {
  const int b = blockIdx.x, lane = threadIdx.x;
  int cnt = 0;
  for (int t = lane; t < TT; t += 64) cnt += (tokens[b * TT + t] != 0) ? 1 : 0;
  #pragma unroll
  for (int off = 32; off >= 1; off >>= 1) cnt += __shfl_down(cnt, off, 64);
  if (lane == 0) { slen[b] = cnt; out_sl[b] = (float)cnt; }
}

// ---------------- K2a: embedding gather -> bf16 A matrix [NT][256] ----------------
__global__ __launch_bounds__(256) void k_embed(const int* __restrict__ tokens,
                                               const float* __restrict__ emb,
                                               ushort16* __restrict__ A) {
  const int f = blockIdx.x * 256 + threadIdx.x;  // float4 group, NT*256/4 total
  const int e = f * 4;
  const int row = e >> 8;
  const int col = e & 255;
  const int tok = tokens[row];
  const float4 v = *(const float4*)(emb + (size_t)tok * 256 + col);
  uint32 lo = (uint32)f2bf(v.x) | ((uint32)f2bf(v.y) << 16);
  uint32 hi = (uint32)f2bf(v.z) | ((uint32)f2bf(v.w) << 16);
  *(uint2*)(A + e) = make_uint2(lo, hi);
}

// ---------------- K2b: BT[c][k] = Wx_{f|b}[k][c] bf16, c in [0,2048) ----------------
__global__ __launch_bounds__(256) void k_wxprep(const float* __restrict__ Wxf,
                                                const float* __restrict__ Wxb,
                                                ushort16* __restrict__ BT) {
  const int id = blockIdx.x * 256 + threadIdx.x;   // 2048*256
  const int c = id >> 8, k = id & 255;
  const float v = (c < G4) ? Wxf[k * G4 + c] : Wxb[k * G4 + (c - G4)];
  BT[c * 256 + k] = f2bf(v);
}

// ---------------- K2c: Wh -> half2 pack, layout [k2][1024] ----------------
__global__ __launch_bounds__(256) void k_whprep(const float* __restrict__ Wh,
                                                uint32* __restrict__ W2) {
  const int id = blockIdx.x * 256 + threadIdx.x;   // 128*1024
  const int k2 = id >> 10, c = id & 1023;
  const float w0 = Wh[(2 * k2) * G4 + c];
  const float w1 = Wh[(2 * k2 + 1) * G4 + c];
  const ushort16 b0 = __builtin_bit_cast(ushort16, (_Float16)w0);
  const ushort16 b1 = __builtin_bit_cast(ushort16, (_Float16)w1);
  W2[id] = ((uint32)b1 << 16) | (uint32)b0;
}

// ---------------- K3: xg GEMM  [NT,256] @ [256,2048] -> bf16 xg (gate-quad layout) ----------------
// Output ushort index = row*1024 + (h_idx)*4 + gate, so k_lstm lane tid reads
// its 4 gate inputs as ONE 8-byte load.
__global__ __launch_bounds__(256) void k_gemm_xg(const ushort16* __restrict__ A,
                                                 const ushort16* __restrict__ BT,
                                                 const float* __restrict__ bias_f,
                                                 const float* __restrict__ bias_b,
                                                 ushort16* __restrict__ xgf,
                                                 ushort16* __restrict__ xgb) {
  __shared__ __align__(16) ushort16 As[64 * 36];
  __shared__ __align__(16) ushort16 Bs[64 * 36];
  const int m0 = blockIdx.x * 64;
  const int n0 = blockIdx.y * 64;
  const int tid = threadIdx.x;
  const int wave = tid >> 6, lane = tid & 63;
  const int lr = tid >> 2;            // staging row 0..63
  const int lc = (tid & 3) * 8;       // staging col {0,8,16,24}
  const int am = lane & 15, aq = lane >> 4;
  floatx4 acc[4];
  #pragma unroll
  for (int j = 0; j < 4; ++j) acc[j] = (floatx4){0.f, 0.f, 0.f, 0.f};

  for (int k0 = 0; k0 < 256; k0 += 32) {
    const uint4 va = *(const uint4*)(A  + ((m0 + lr) * 256 + k0 + lc));
    const uint4 vb = *(const uint4*)(BT + ((n0 + lr) * 256 + k0 + lc));
    *(uint2*)&As[lr * 36 + lc]     = make_uint2(va.x, va.y);
    *(uint2*)&As[lr * 36 + lc + 4] = make_uint2(va.z, va.w);
    *(uint2*)&Bs[lr * 36 + lc]     = make_uint2(vb.x, vb.y);
    *(uint2*)&Bs[lr * 36 + lc + 4] = make_uint2(vb.z, vb.w);
    __syncthreads();
    union { uint2 u[2]; short8 s; } fa, fb;
    fa.u[0] = *(const uint2*)&As[(wave * 16 + am) * 36 + aq * 8];
    fa.u[1] = *(const uint2*)&As[(wave * 16 + am) * 36 + aq * 8 + 4];
    #pragma unroll
    for (int j = 0; j < 4; ++j) {
      fb.u[0] = *(const uint2*)&Bs[(j * 16 + am) * 36 + aq * 8];
      fb.u[1] = *(const uint2*)&Bs[(j * 16 + am) * 36 + aq * 8 + 4];
      acc[j] = __builtin_amdgcn_mfma_f32_16x16x32_bf16(fa.s, fb.s, acc[j], 0, 0, 0);
    }
    __syncthreads();
  }
  // C/D layout (m89/m91-verified): col = lane&15, row = (lane>>4)*4 + reg
  const int orow = m0 + wave * 16 + aq * 4;
  #pragma unroll
  for (int j = 0; j < 4; ++j) {
    const int col = n0 + j * 16 + am;
    const float bv = (col < G4) ? bias_f[col] : bias_b[col - G4];
    const int cc = col & 1023;
    const int poff = ((cc & 255) << 2) + (cc >> 8);   // h_idx*4 + gate
    ushort16* dst = (col < G4) ? xgf : xgb;
    #pragma unroll
    for (int r = 0; r < 4; ++r) {
      const float v = acc[j][r] + bv;
      const int row = orow + r;
      dst[(size_t)row * G4 + poff] = f2bf(v);
    }
  }
}

// ---------------- K4: LSTM recurrence v6 — AGPR+VGPR+LDS residency ----------------
// k2 ordering: [0,KA) AGPR, [KA,KA+KV) VGPR, [KA+KV,128) LDS.
__global__ __launch_bounds__(256, 1) void k_lstm(const uint2* __restrict__ xg4f,
                                                 const uint2* __restrict__ xg4b,
                                                 const uint32* __restrict__ Whf,
                                                 const uint32* __restrict__ Whb,
                                                 float* __restrict__ enc) {
  __shared__ __align__(16) uint4  WLs[KL * 256];    // 102400 B
  __shared__ __align__(16) uint32 h2buf[2 * 128];   // 1 KB packed f16 h
  const int bi = blockIdx.x;
  const int dir = bi >> 6, b = bi & 63;
  const int tid = threadIdx.x;
  const uint2* xg = dir ? xg4b : xg4f;   // gate-quad layout: uint2 idx = row*256 + tid
  const uint32* W2 = dir ? Whb : Whf;

  // LDS-resident rows as per-lane uint4.
  for (int r = 0; r < KL; ++r) {
    const uint32* src = W2 + (KA + KV + r) * 1024 + tid;
    WLs[r * 256 + tid] = make_uint4(src[0], src[256], src[512], src[768]);
  }
  // AGPR-resident rows: park once via v_accvgpr_write (r4-proven mechanism).
  uint32 agA[KA], agB[KA], agC[KA], agD[KA];
  #pragma unroll
  for (int i = 0; i < KA; ++i) {
    const uint32* src = W2 + i * 1024 + tid;
    const uint32 x0 = src[0], x1 = src[256], x2 = src[512], x3 = src[768];
    asm volatile("v_accvgpr_write_b32 %0, %1" : "=a"(agA[i]) : "v"(x0));
    asm volatile("v_accvgpr_write_b32 %0, %1" : "=a"(agB[i]) : "v"(x1));
    asm volatile("v_accvgpr_write_b32 %0, %1" : "=a"(agC[i]) : "v"(x2));
    asm volatile("v_accvgpr_write_b32 %0, %1" : "=a"(agD[i]) : "v"(x3));
  }
  // VGPR-resident rows (172 regs; fits under the 256 arch-VGPR cap).
  uint4 wv[KV];
  #pragma unroll
  for (int i = 0; i < KV; ++i) {
    const uint32* src = W2 + (KA + i) * 1024 + tid;
    wv[i] = make_uint4(src[0], src[256], src[512], src[768]);
  }
  #pragma unroll
  for (int i = 0; i < KV; ++i)
    asm volatile("" : "+v"(wv[i].x), "+v"(wv[i].y), "+v"(wv[i].z), "+v"(wv[i].w));

  if (tid < 128) h2buf[tid] = 0u;
  float c_state = 0.f;
  __syncthreads();

  const int t0 = dir ? (TT - 1) : 0;
  uint2 xp = xg[(size_t)(b * TT + t0) * 256 + tid];

  for (int s = 0; s < TT; ++s) {
    float a0 = bf2f((ushort16)(xp.x & 0xffffu));
    float a1 = bf2f((ushort16)(xp.x >> 16));
    float a2 = bf2f((ushort16)(xp.y & 0xffffu));
    float a3 = bf2f((ushort16)(xp.y >> 16));
    if (s + 1 < TT) {
      const int t1 = dir ? (TT - 2 - s) : (s + 1);
      xp = xg[(size_t)(b * TT + t1) * 256 + tid];
    }
    const uint4* hb = (const uint4*)(h2buf + (s & 1) * 128);
    #pragma unroll
    for (int blk = 0; blk < 32; ++blk) {
      const uint4 hq = hb[blk];                 // wave-uniform b128 broadcast
      #pragma unroll
      for (int j = 0; j < 4; ++j) {
        const int k2 = blk * 4 + j;
        const uint32 hu = (j == 0) ? hq.x : (j == 1) ? hq.y : (j == 2) ? hq.z : hq.w;
        const half2t hh = __builtin_bit_cast(half2t, hu);
        if (k2 < KA) {
          uint32 w0, w1, w2_, w3;
          asm volatile("v_accvgpr_read_b32 %0, %1" : "=v"(w0)  : "a"(agA[k2]));
          asm volatile("v_accvgpr_read_b32 %0, %1" : "=v"(w1)  : "a"(agB[k2]));
          asm volatile("v_accvgpr_read_b32 %0, %1" : "=v"(w2_) : "a"(agC[k2]));
          asm volatile("v_accvgpr_read_b32 %0, %1" : "=v"(w3)  : "a"(agD[k2]));
          a0 = fdot2_(w0, hh, a0);
          a1 = fdot2_(w1, hh, a1);
          a2 = fdot2_(w2_, hh, a2);
          a3 = fdot2_(w3, hh, a3);
        } else if (k2 < KA + KV) {
          const uint4 wq = wv[k2 - KA];
          a0 = fdot2_(wq.x, hh, a0);
          a1 = fdot2_(wq.y, hh, a1);
          a2 = fdot2_(wq.z, hh, a2);
          a3 = fdot2_(wq.w, hh, a3);
        } else {
          const uint4 wq = WLs[(k2 - KA - KV) * 256 + tid];
          a0 = fdot2_(wq.x, hh, a0);
          a1 = fdot2_(wq.y, hh, a1);
          a2 = fdot2_(wq.z, hh, a2);
          a3 = fdot2_(wq.w, hh, a3);
        }
      }
    }
    // Nonlinearity + state update, all lane-local.
    c_state = sigf(a1) * c_state + sigf(a0) * tanhf_(a2);
    const float h = sigf(a3) * tanhf_(c_state);
    const int row = b * TT + (dir ? (TT - 1 - s) : s);
    enc[(size_t)row * 512 + dir * 256 + tid] = h;
    // pack h -> f16 pairs; even lanes write one dword (conflict-free)
    const int hv = (int)(uint32)__builtin_bit_cast(ushort16, (_Float16)h);
    const int ho = __shfl_xor(hv, 1, 64);
    if (!(tid & 1))
      h2buf[((s + 1) & 1) * 128 + (tid >> 1)] =
          ((uint32)hv & 0xffffu) | ((uint32)ho << 16);
    __syncthreads();
  }
}

// ---------------- K5: logits = enc @ W_dense + b ----------------
__global__ __launch_bounds__(256) void k_dense(const float* __restrict__ enc,
                                               const float* __restrict__ Wd,
                                               const float* __restrict__ bd,
                                               float* __restrict__ logits) {
  __shared__ float Wl[512 * NL];
  __shared__ float bl[NL];
  const int tid = threadIdx.x;
  for (int i = tid; i < 512 * NL; i += 256) Wl[i] = Wd[i];
  if (tid < NL) bl[tid] = bd[tid];
  __syncthreads();
  const int wave = tid >> 6, lane = tid & 63;
  const int row = blockIdx.x * 4 + wave;
  const float* er = enc + (size_t)row * 512;
  float p[NL];
  #pragma unroll
  for (int c = 0; c < NL; ++c) p[c] = 0.f;
  #pragma unroll
  for (int u = 0; u < 8; ++u) {
    const int k = u * 64 + lane;
    const float v = er[k];
    const float* wr = &Wl[k * NL];
    #pragma unroll
    for (int c = 0; c < NL; ++c) p[c] += v * wr[c];
  }
  #pragma unroll
  for (int c = 0; c < NL; ++c) {
    #pragma unroll
    for (int off = 32; off >= 1; off >>= 1) p[c] += __shfl_down(p[c], off, 64);
  }
  if (lane == 0) {
    float* orow = logits + (size_t)row * NL;
    #pragma unroll
    for (int c = 0; c < NL; ++c) orow[c] = p[c] + bl[c];
  }
}

// ---------------- K6: CRF log-likelihood ----------------
__global__ __launch_bounds__(64) void k_crf(const float* __restrict__ logits,
                                            const int* __restrict__ labels,
                                            const int* __restrict__ slen,
                                            const float* __restrict__ trans,
                                            float* __restrict__ out_ll) {
  __shared__ float tr[NL * NL];
  __shared__ float alpha[NL];
  const int b = blockIdx.x;
  const int lane = threadIdx.x;
  for (int i = lane; i < NL * NL; i += 64) tr[i] = trans[i];
  __syncthreads();
  const int len = slen[b];
  const int* tg = labels + b * TT;
  const float* lg = logits + (size_t)b * TT * NL;
  float s = 0.f;
  for (int t = lane; t < TT; t += 64)
    if (t < len) s += lg[t * NL + tg[t]];
  for (int t = lane; t < TT - 1; t += 64)
    if (t + 1 < len) s += tr[tg[t] * NL + tg[t + 1]];
  #pragma unroll
  for (int off = 32; off >= 1; off >>= 1) s += __shfl_down(s, off, 64);
  if (lane < NL) alpha[lane] = lg[lane];
  __syncthreads();
  if (lane < NL) {
    const int j = lane;
    for (int t = 1; t < TT; ++t) {
      if (t < len) {
        float av[NL];
        float m = -1e30f;
        #pragma unroll
        for (int i = 0; i < NL; ++i) { av[i] = alpha[i] + tr[i * NL + j]; m = fmaxf(m, av[i]); }
        float ss = 0.f;
        #pragma unroll
        for (int i = 0; i < NL; ++i) ss += __expf(av[i] - m);
        const float nj = m + __logf(ss) + lg[t * NL + j];
        alpha[j] = nj;
      }
    }
  }
  __syncthreads();
  if (lane == 0) {
    float m = -1e30f;
    #pragma unroll
    for (int i = 0; i < NL; ++i) m = fmaxf(m, alpha[i]);
    float ss = 0.f;
    #pragma unroll
    for (int i = 0; i < NL; ++i) ss += __expf(alpha[i] - m);
    out_ll[b] = s - (m + __logf(ss));
  }
}

extern "C" void kernel_launch(void* const* d_in, const int* in_sizes, int n_in,
                              void* d_out, int out_size, void* d_ws, size_t ws_size,
                              hipStream_t stream) {
  (void)in_sizes; (void)n_in; (void)out_size; (void)ws_size;
  const int*   tokens = (const int*)d_in[0];
  const int*   labels = (const int*)d_in[1];
  const float* emb    = (const float*)d_in[2];
  const float* Wxf    = (const float*)d_in[3];
  const float* Whf    = (const float*)d_in[4];
  const float* bf_    = (const float*)d_in[5];
  const float* Wxb    = (const float*)d_in[6];
  const float* Whb    = (const float*)d_in[7];
  const float* bb_    = (const float*)d_in[8];
  const float* Wd     = (const float*)d_in[9];
  const float* bd     = (const float*)d_in[10];
  const float* trans  = (const float*)d_in[11];
  float* out = (float*)d_out;   // [logits 294912][seq_len 64][ll 64]

  char* ws = (char*)d_ws;
  ushort16* A    = (ushort16*)(ws + 0);           // 16 MB  bf16 emb rows
  ushort16* BT   = (ushort16*)(ws + 16777216);    //  1 MB  Wx^T bf16 (2048x256)
  uint32*   W2f  = (uint32*)  (ws + 17825792);    // 512 KB Wh_f half2 [128][1024]
  uint32*   W2b  = (uint32*)  (ws + 18350080);    // 512 KB
  ushort16* xgf  = (ushort16*)(ws + 18874368);    // 64 MB  bf16 gate-quad [NT][1024]
  ushort16* xgb  = (ushort16*)(ws + 85983232);    // 64 MB
  float*    enc  = (float*)   (ws + 153092096);   // 64 MB  fp32 [NT][512]
  int*      slen = (int*)     (ws + 220200960);   // 256 B

  k_seqlen<<<BB, 64, 0, stream>>>(tokens, slen, out + NT * NL);
  k_embed <<<NT * 256 / 4 / 256, 256, 0, stream>>>(tokens, emb, A);
  k_wxprep<<<2048 * 256 / 256, 256, 0, stream>>>(Wxf, Wxb, BT);
  k_whprep<<<128 * 1024 / 256, 256, 0, stream>>>(Whf, W2f);
  k_whprep<<<128 * 1024 / 256, 256, 0, stream>>>(Whb, W2b);
  k_gemm_xg<<<dim3(NT / 64, 2048 / 64), 256, 0, stream>>>(A, BT, bf_, bb_, xgf, xgb);
  k_lstm  <<<128, 256, 0, stream>>>((const uint2*)xgf, (const uint2*)xgb, W2f, W2b, enc);
  k_dense <<<NT / 4, 256, 0, stream>>>(enc, Wd, bd, out);
  k_crf   <<<BB, 64, 0, stream>>>(out, labels, slen, trans, out + NT * NL + BB);
}